// Round 1
// baseline (179.981 us; speedup 1.0000x reference)
//
#include <hip/hip_runtime.h>
#include <hip/hip_bf16.h>

typedef __bf16 bf16_t;
typedef __bf16 bf16x4 __attribute__((ext_vector_type(4)));
typedef __bf16 bf16x8 __attribute__((ext_vector_type(8)));
typedef float f32x4 __attribute__((ext_vector_type(4)));

#define NTOK 49152   // s*h*w = 3*128*128 tokens per batch
#define CDIM 128
#define CHUNKS 128   // split-K chunks for the Gram (grid = 2*128 = 256 -> 1 block/CU, balanced)
#define KT 384       // tokens per chunk
#define STEPS 12     // KT/32

__device__ inline f32x4 mfma16(bf16x8 a, bf16x8 b, f32x4 c) {
  return __builtin_amdgcn_mfma_f32_16x16x32_bf16(a, b, c, 0, 0, 0);
}

// Raw barrier: lgkmcnt(0) only (ds_writes visible), NO vmcnt drain -> the
// prefetch global loads stay in flight across the barrier (T4 pattern).
#define BARRIER() do { asm volatile("s_waitcnt lgkmcnt(0)" ::: "memory"); \
    __builtin_amdgcn_s_barrier(); } while (0)

// ---------------------------------------------------------------------------
// K1: per-batch token Gram S = X X^T, split-K fp32 partials.
// grid 256 = b(2) x chunk(128), exactly 1 block/CU (balanced; old 384 left
// half the CUs with 2 blocks). Per-step pipeline: loads for step k+2 issued
// before the LDS write of step k+1's data (compiler inserts counted vmcnt(4),
// not 0), raw s_barrier keeps them in flight -> full-phase HBM latency cover
// at 1 wave/SIMD. LDS staging packed as bf16x4 (ds_write_b64, 4/thread).
// Partials stored in RAW FRAGMENT ORDER as contiguous f32x4 (16 stores/thread,
// 1KB/wave runs) -- k2b un-permutes. Old: 64 scalar stores/thread.
// ---------------------------------------------------------------------------
__global__ __launch_bounds__(256) void k1_gram(const float* __restrict__ x,
                                               float* __restrict__ part) {
  const int blk = blockIdx.x;
  const int b = blk >> 7, chunk = blk & 127;
  const float* Xb = x + (size_t)b * CDIM * NTOK;
  const int tid = threadIdx.x, wave = tid >> 6, lane = tid & 63;

  __shared__ __align__(16) bf16_t tile[2][128 * 32];  // frag-ordered, 8 KB each

  // Staging map: thread t -> ch = t>>1, half = t&1 (16 toks each).
  const int sch = tid >> 1, shalf = tid & 1;
  const float* gsrc = Xb + (size_t)sch * NTOK + chunk * KT + shalf * 16;
  // 16B-chunk ids for this thread's two 8-token groups (within a 32-tok step)
  const int c16base = ((sch >> 4) << 6) + (sch & 15);
  const int cg0 = c16base + ((shalf * 2) << 4);
  const int cg1 = c16base + ((shalf * 2 + 1) << 4);

  f32x4 stA[4], stB[4];
#define STAGE_LOAD(st, step)                               \
  {                                                        \
    const float* p_ = gsrc + (step) * 32;                  \
    st[0] = *(const f32x4*)(p_ + 0);                       \
    st[1] = *(const f32x4*)(p_ + 4);                       \
    st[2] = *(const f32x4*)(p_ + 8);                       \
    st[3] = *(const f32x4*)(p_ + 12);                      \
  }
#define CVT4(v) (bf16x4){(bf16_t)(v)[0], (bf16_t)(v)[1], (bf16_t)(v)[2], (bf16_t)(v)[3]}
#define STAGE_WRITE(st, buf)                               \
  {                                                        \
    bf16_t* t_ = &tile[buf][0];                            \
    *(bf16x4*)&t_[cg0 * 8 + 0] = CVT4(st[0]);              \
    *(bf16x4*)&t_[cg0 * 8 + 4] = CVT4(st[1]);              \
    *(bf16x4*)&t_[cg1 * 8 + 0] = CVT4(st[2]);              \
    *(bf16x4*)&t_[cg1 * 8 + 4] = CVT4(st[3]);              \
  }

  f32x4 acc[2][8];
#pragma unroll
  for (int t = 0; t < 2; ++t)
#pragma unroll
    for (int j = 0; j < 8; ++j) acc[t][j] = (f32x4){0.f, 0.f, 0.f, 0.f};

#define MFMA_PHASE(buf)                                                     \
  {                                                                         \
    bf16x8 frag[8];                                                         \
    _Pragma("unroll")                                                       \
    for (int g = 0; g < 8; ++g)                                             \
      frag[g] = *(const bf16x8*)&tile[buf][(g * 64 + lane) * 8];            \
    bf16x8 a0, a1;                                                          \
    if (wave == 0)      { a0 = frag[0]; a1 = frag[1]; }                     \
    else if (wave == 1) { a0 = frag[2]; a1 = frag[3]; }                     \
    else if (wave == 2) { a0 = frag[4]; a1 = frag[5]; }                     \
    else                { a0 = frag[6]; a1 = frag[7]; }                     \
    _Pragma("unroll")                                                       \
    for (int j = 0; j < 8; ++j) {                                           \
      acc[0][j] = mfma16(a0, frag[j], acc[0][j]);                           \
      acc[1][j] = mfma16(a1, frag[j], acc[1][j]);                           \
    }                                                                       \
  }

  // Prologue: tile0 -> LDS0, tile1 loads in flight across the barrier.
  STAGE_LOAD(stA, 0);
  STAGE_WRITE(stA, 0);
  STAGE_LOAD(stB, 1);
  BARRIER();

  for (int kk = 0; kk < STEPS; kk += 2) {
    // phase A: compute tile kk (buf0); write tile kk+1 (stB->buf1); load kk+2
    if (kk + 2 < STEPS) STAGE_LOAD(stA, kk + 2);
    STAGE_WRITE(stB, 1);        // auto vmcnt(4): waits stB only, stA flies on
    MFMA_PHASE(0);
    BARRIER();
    // phase B: compute tile kk+1 (buf1); write tile kk+2 (stA->buf0); load kk+3
    if (kk + 3 < STEPS) STAGE_LOAD(stB, kk + 3);
    if (kk + 2 < STEPS) STAGE_WRITE(stA, 0);
    MFMA_PHASE(1);
    BARRIER();
  }
#undef STAGE_LOAD
#undef STAGE_WRITE
#undef MFMA_PHASE

  // Fragment-order partial dump: element E = (t*8+j)*1024 + tid*4 + reg.
  // (row = wave*32 + t*16 + quad*4 + reg, col = j*16 + r) decoded in k2b.
  float* pb = part + ((size_t)(b * CHUNKS + chunk) << 14);
#pragma unroll
  for (int t = 0; t < 2; ++t)
#pragma unroll
    for (int j = 0; j < 8; ++j)
      *(f32x4*)&pb[((((t * 8 + j) << 8) + tid) << 2)] = acc[t][j];
}

// ---------------------------------------------------------------------------
// K2a: reduce 128 chunks -> 8 slice-partials of 16 chunks each (layout-agnostic).
// ---------------------------------------------------------------------------
__global__ __launch_bounds__(256) void k2a_reduce(const float* __restrict__ part,
                                                  float* __restrict__ part2) {
  const int gid = blockIdx.x * 256 + threadIdx.x;  // 65536 threads
  const int e4 = gid & 4095, sl = (gid >> 12) & 7, b = gid >> 15;
  const float* p = part + ((size_t)(b * CHUNKS + sl * 16) << 14) + e4 * 4;
  f32x4 s = (f32x4){0.f, 0.f, 0.f, 0.f};
#pragma unroll 8
  for (int i = 0; i < 16; ++i) s += *(const f32x4*)(p + ((size_t)i << 14));
  *(f32x4*)(part2 + ((size_t)(b * 8 + sl) << 14) + e4 * 4) = s;
}

// ---------------------------------------------------------------------------
// K2b: sum 8 slices and un-permute fragment order -> S[2][128][128] fp32.
// ---------------------------------------------------------------------------
__global__ __launch_bounds__(256) void k2b_reduce(const float* __restrict__ part2,
                                                  float* __restrict__ S) {
  const int gid = blockIdx.x * 256 + threadIdx.x;  // 8192 threads
  const int g4 = gid & 4095, b = gid >> 12;
  f32x4 s = (f32x4){0.f, 0.f, 0.f, 0.f};
#pragma unroll
  for (int sl = 0; sl < 8; ++sl)
    s += *(const f32x4*)(part2 + ((size_t)(b * 8 + sl) << 14) + g4 * 4);
  const int tj = g4 >> 8, t = tj >> 3, j = tj & 7;
  const int tid2 = g4 & 255, wave = tid2 >> 6, quad = (tid2 >> 4) & 3, r = tid2 & 15;
  const int row0 = wave * 32 + t * 16 + quad * 4, col = j * 16 + r;
  float* Sb = S + ((size_t)b << 14);
#pragma unroll
  for (int reg = 0; reg < 4; ++reg) Sb[(row0 + reg) * 128 + col] = s[reg];
}

// ---------------------------------------------------------------------------
// K3a: T[b][t][i][j] = sum_c W_t[i][c] * S_b[j][c]  (t=0:Wk, 1:Wq; S symmetric)
// ---------------------------------------------------------------------------
__global__ __launch_bounds__(256) void k3_t(const float* __restrict__ S,
                                            const float* __restrict__ Wk,
                                            const float* __restrict__ Wq,
                                            float* __restrict__ Tm) {
  const int idx = blockIdx.x * 256 + threadIdx.x;  // 0..65535
  const int j = idx & 127, i = (idx >> 7) & 127, t = (idx >> 14) & 1, b = idx >> 15;
  const f32x4* w4 = (const f32x4*)((t ? Wq : Wk) + i * 128);
  const f32x4* s4 = (const f32x4*)(S + (b << 14) + j * 128);
  float s = 0.f;
#pragma unroll 8
  for (int q = 0; q < 32; ++q) {
    const f32x4 a = w4[q], v = s4[q];
    s += a[0] * v[0] + a[1] * v[1] + a[2] * v[2] + a[3] * v[3];
  }
  Tm[idx] = s;
}

// ---------------------------------------------------------------------------
// K3b: per (b,head): G = Wk S Wq^T, norms from diagonals, softmax -> attn
// ---------------------------------------------------------------------------
__global__ __launch_bounds__(256) void k3_attn(const float* __restrict__ Tm,
                                               const float* __restrict__ Wk,
                                               const float* __restrict__ Wq,
                                               const float* __restrict__ resc,
                                               float* __restrict__ attn) {
  const int blk = blockIdx.x;  // 16 = b*8+h
  const int b = blk >> 3, h = blk & 7;
  const int tid = threadIdx.x, d = tid >> 4, e = tid & 15;
  const float* Tk = Tm + (size_t)(b * 2 + 0) * 16384;
  const float* Tq = Tm + (size_t)(b * 2 + 1) * 16384;

  const float* tkrow = Tk + (h * 16 + d) * 128;
  const float* wqrow = Wq + (h * 16 + e) * 128;
  float g = 0.f;
#pragma unroll 4
  for (int c = 0; c < 128; ++c) g += tkrow[c] * wqrow[c];

  __shared__ float sqk[16], sqq[16];
  if (e == 0) {
    const float* wkrow = Wk + (h * 16 + d) * 128;
    float s = 0.f;
    for (int c = 0; c < 128; ++c) s += tkrow[c] * wkrow[c];
    sqk[d] = s;
  }
  if (d == 0) {
    const float* tqrow = Tq + (h * 16 + e) * 128;
    float s = 0.f;
    for (int c = 0; c < 128; ++c) s += tqrow[c] * wqrow[c];
    sqq[e] = s;
  }
  __syncthreads();

  const float nk = fmaxf(sqrtf(fmaxf(sqk[d], 0.f)), 1e-12f);
  const float nq = fmaxf(sqrtf(fmaxf(sqq[e], 0.f)), 1e-12f);
  float pre = g / (nk * nq) * resc[h];

  float mx = pre;
#pragma unroll
  for (int m = 1; m < 16; m <<= 1) mx = fmaxf(mx, __shfl_xor(mx, m, 64));
  const float p = expf(pre - mx);
  float sum = p;
#pragma unroll
  for (int m = 1; m < 16; m <<= 1) sum += __shfl_xor(sum, m, 64);
  attn[blk * 256 + tid] = p / sum;
}

// ---------------------------------------------------------------------------
// K3c: P[b] = Wp * blockdiag(attn[b]) * Wv, stored bf16 (P rounding adds <2e-3).
// ---------------------------------------------------------------------------
__global__ __launch_bounds__(256) void k3_p(const float* __restrict__ attn,
                                            const float* __restrict__ Wp,
                                            const float* __restrict__ Wv,
                                            bf16_t* __restrict__ Phi) {
  const int blk = blockIdx.x;  // 256 = b*128 + row
  const int b = blk >> 7, rrow = blk & 127;
  const int tid = threadIdx.x;
  __shared__ float M[128];
  if (tid < 128) {
    const int h = tid >> 4, e = tid & 15;
    const float* A = attn + (size_t)(b * 8 + h) * 256;
    const float* wp = Wp + rrow * 128 + h * 16;
    float m = 0.f;
#pragma unroll
    for (int d = 0; d < 16; ++d) m += wp[d] * A[d * 16 + e];
    M[tid] = m;
  }
  __syncthreads();
  if (tid < 128) {
    const int c = tid;
    float p = 0.f;
#pragma unroll 4
    for (int j = 0; j < 128; ++j) p += M[j] * Wv[j * 128 + c];
    Phi[((size_t)b << 14) + rrow * 128 + c] = (bf16_t)p;
  }
}

// ---------------------------------------------------------------------------
// K4: out[b] = P_b * X_b + bp, fp32 out, native layout. grid 1536 = b x 768
// tiles of 64 tokens. X staged fp32->bf16 in fragment order (as before).
// NEW epilogue: acc is transposed through LDS (reusing the staging buffer,
// stride 68 floats to break the quad-collapse bank conflict) so stores are
// f32x4 in 256-B-contiguous runs: 8 vector stores/thread vs 32 scalar.
// ---------------------------------------------------------------------------
__global__ __launch_bounds__(256) void k4_out(const float* __restrict__ x,
                                              const bf16_t* __restrict__ Phi,
                                              const float* __restrict__ bp,
                                              float* __restrict__ out) {
  const int blk = blockIdx.x;
  const int b = blk / 768, tg = blk % 768;
  const float* Xb = x + (size_t)b * CDIM * NTOK;
  const bf16_t* Ph = Phi + ((size_t)b << 14);
  float* Ob = out + (size_t)b * CDIM * NTOK;
  const int tid = threadIdx.x, wave = tid >> 6, lane = tid & 63;
  const int r = lane & 15, quad = lane >> 4;
  const int tok0 = tg * 64;

  // 17408 B: bf16 tile[128*64] (16 KB) for staging, then float[64][68] for
  // the store transpose. 6 blocks/CU * 17.4 KB = 104 KB LDS -> occupancy kept.
  __shared__ __align__(16) char smem[64 * 68 * 4];
  bf16_t* tile = (bf16_t*)smem;
  float* tbuf = (float*)smem;

  // Stage: thread t -> ch = t>>1, half = t&1 (32 toks each), coalesced f32x4.
  {
    const int sch = tid >> 1, shalf = tid & 1;
    const float* p = Xb + (size_t)sch * NTOK + tok0 + shalf * 32;
    f32x4 st[8];
#pragma unroll
    for (int q = 0; q < 8; ++q) st[q] = *(const f32x4*)(p + q * 4);
    const int chunk_hi = ((sch >> 5) << 8) + (((sch >> 3) & 3) << 4);
    const int ei = sch & 7;
#pragma unroll
    for (int j = 0; j < 32; ++j) {
      const int tok = shalf * 32 + j;
      const int chunk = chunk_hi + ((tok >> 4) << 6) + (tok & 15);
      tile[chunk * 8 + ei] = (bf16_t)st[j >> 2][j & 3];
    }
  }
  __syncthreads();

  f32x4 acc[8];
#pragma unroll
  for (int m = 0; m < 8; ++m) acc[m] = (f32x4){0.f, 0.f, 0.f, 0.f};

#pragma unroll
  for (int step = 0; step < 4; ++step) {  // kb = step*32
    const bf16x8 bfr = *(const bf16x8*)&tile[(step * 256 + wave * 64 + lane) * 8];
#pragma unroll
    for (int m = 0; m < 8; ++m) {
      const bf16x8 ah = *(const bf16x8*)(Ph + (16 * m + r) * 128 + step * 32 + quad * 8);
      acc[m] = mfma16(ah, bfr, acc[m]);
    }
  }

  __syncthreads();  // all waves done reading tile before reuse as tbuf
#pragma unroll
  for (int half = 0; half < 2; ++half) {
    // scatter this half's acc rows (64 rows x 64 toks) into tbuf
#pragma unroll
    for (int mm = 0; mm < 4; ++mm) {
#pragma unroll
      for (int reg = 0; reg < 4; ++reg)
        tbuf[(mm * 16 + quad * 4 + reg) * 68 + wave * 16 + r] = acc[half * 4 + mm][reg];
    }
    __syncthreads();
    // coalesced vector stores: 16 lanes cover one row's 64 toks (256 B run)
#pragma unroll
    for (int rep = 0; rep < 4; ++rep) {
      const int idx = rep * 256 + tid, rloc = idx >> 4, g = idx & 15;
      f32x4 v = *(const f32x4*)&tbuf[rloc * 68 + g * 4];
      const int row = half * 64 + rloc;
      const float bb = bp[row];
      v[0] += bb; v[1] += bb; v[2] += bb; v[3] += bb;
      *(f32x4*)&Ob[(size_t)row * NTOK + tok0 + g * 4] = v;
    }
    if (half == 0) __syncthreads();
  }
}

extern "C" void kernel_launch(void* const* d_in, const int* in_sizes, int n_in,
                              void* d_out, int out_size, void* d_ws, size_t ws_size,
                              hipStream_t stream) {
  const float* x    = (const float*)d_in[0];
  const float* Wq   = (const float*)d_in[1];
  const float* Wk   = (const float*)d_in[2];
  const float* Wv   = (const float*)d_in[3];
  const float* Wp   = (const float*)d_in[4];
  const float* bp   = (const float*)d_in[5];
  const float* resc = (const float*)d_in[6];
  float* out = (float*)d_out;

  // Small scratch in d_ws (<= 442 KB used).
  char* ws = (char*)d_ws;
  float*  S    = (float*)(ws + 0);        // 131072 B
  float*  Tm   = (float*)(ws + 131072);   // 262144 B
  float*  attn = (float*)(ws + 393216);   //  16384 B
  bf16_t* Phi  = (bf16_t*)(ws + 409600);  //  65536 B
  // Big scratch inside d_out (50.3 MB): partials 16 MB + part2 1 MB, both
  // consumed (k2a/k2b) before k4 overwrites d_out with the real output.
  float* part  = (float*)d_out;                      // 16 MB
  float* part2 = (float*)((char*)d_out + 16777216);  //  1 MB

  k1_gram<<<2 * CHUNKS, 256, 0, stream>>>(x, part);
  k2a_reduce<<<256, 256, 0, stream>>>(part, part2);
  k2b_reduce<<<32, 256, 0, stream>>>(part2, S);
  k3_t<<<256, 256, 0, stream>>>(S, Wk, Wq, Tm);
  k3_attn<<<16, 256, 0, stream>>>(Tm, Wk, Wq, resc, attn);
  k3_p<<<256, 256, 0, stream>>>(attn, Wp, Wv, Phi);
  k4_out<<<1536, 256, 0, stream>>>(x, Phi, bp, out);
}